// Round 1
// baseline (6152.380 us; speedup 1.0000x reference)
//
#include <hip/hip_runtime.h>

#define T_PTS 100000
#define NB 2
#define GCELLS 32768
#define HID 128
#define KD 256
#define PTILE 32
#define TPB 3125   /* T_PTS / PTILE */
#define XSTR 260   /* padded row stride for xs (floats) */

__device__ __forceinline__ unsigned enc_f(float f) {
  unsigned u = __float_as_uint(f);
  return (u & 0x80000000u) ? ~u : (u | 0x80000000u);
}
__device__ __forceinline__ float dec_f(unsigned e) {
  return __uint_as_float((e & 0x80000000u) ? (e & 0x7FFFFFFFu) : ~e);
}
__device__ __forceinline__ void fma4(float* acc, float s, float4 w) {
  acc[0] = fmaf(s, w.x, acc[0]);
  acc[1] = fmaf(s, w.y, acc[1]);
  acc[2] = fmaf(s, w.z, acc[2]);
  acc[3] = fmaf(s, w.w, acc[3]);
}

// One fused resnet block over a tile of 32 points.
// MODE 0: x = points @ fc_pos_w + fc_pos_b           (first block)
// MODE 1: x = [net, decode(cellmax[idx])]            (blocks 1..4)
// y  = relu(x) @ w0            (no bias yet)
// h  = relu(y + b0)            (stored into xs[.][0:128], x is dead)
// out = x @ sw + h @ w1 + b1   -> net_out
template <int MODE>
__global__ __launch_bounds__(256, 3) void resblock_kernel(
    const float* __restrict__ src, const float* __restrict__ posw,
    const float* __restrict__ posb, const unsigned* __restrict__ cell,
    const int* __restrict__ idx, const float* __restrict__ w0,
    const float* __restrict__ b0, const float* __restrict__ w1,
    const float* __restrict__ b1, const float* __restrict__ sw,
    float* __restrict__ net_out) {
  __shared__ float xs[PTILE][XSTR];
  const int tid = threadIdx.x;
  const int b = blockIdx.x / TPB;
  const int t0 = (blockIdx.x % TPB) * PTILE;

  if (MODE == 0) {
    const int pt = tid >> 3;
    const int k0 = (tid & 7) * 32;
    const float* pp = src + ((long)(b * T_PTS + t0 + pt)) * 3;
    const float p0 = pp[0], p1 = pp[1], p2 = pp[2];
#pragma unroll
    for (int j = 0; j < 32; j += 4) {
      float4 wa = *(const float4*)(posw + k0 + j);
      float4 wb = *(const float4*)(posw + 256 + k0 + j);
      float4 wc = *(const float4*)(posw + 512 + k0 + j);
      float4 bb = *(const float4*)(posb + k0 + j);
      float4 r;
      r.x = fmaf(p0, wa.x, fmaf(p1, wb.x, fmaf(p2, wc.x, bb.x)));
      r.y = fmaf(p0, wa.y, fmaf(p1, wb.y, fmaf(p2, wc.y, bb.y)));
      r.z = fmaf(p0, wa.z, fmaf(p1, wb.z, fmaf(p2, wc.z, bb.z)));
      r.w = fmaf(p0, wa.w, fmaf(p1, wb.w, fmaf(p2, wc.w, bb.w)));
      *(float4*)(&xs[pt][k0 + j]) = r;
    }
  } else {
    const int pt = tid >> 3;
    const int c0 = (tid & 7) * 16;
    const long prow = (long)(b * T_PTS + t0 + pt);
    const float* np = src + prow * HID;
    const int g = idx[prow];
    const unsigned* cp = cell + ((long)(b * GCELLS + g)) * HID;
#pragma unroll
    for (int j = 0; j < 16; j += 4) {
      *(float4*)(&xs[pt][c0 + j]) = *(const float4*)(np + c0 + j);
      uint4 e = *(const uint4*)(cp + c0 + j);
      float4 d;
      d.x = dec_f(e.x); d.y = dec_f(e.y); d.z = dec_f(e.z); d.w = dec_f(e.w);
      *(float4*)(&xs[pt][HID + c0 + j]) = d;
    }
  }
  __syncthreads();

  const int pc = tid & 15;
  const int pr = tid >> 4;
  const int p0 = pr * 2, p1 = p0 + 1;
  const int ca = pc * 4, cb = 64 + pc * 4;

  float accy[16];  // relu(x)@w0 : [pt(2)][colquad(2)][4]
  float acco[16];  // x@sw  (later += h@w1)
#pragma unroll
  for (int i = 0; i < 16; ++i) { accy[i] = 0.f; acco[i] = 0.f; }

  // GEMM1 + GEMM3 fused over K=256
  for (int k = 0; k < KD; k += 4) {
    float4 xa4 = *(const float4*)(&xs[p0][k]);
    float4 xb4 = *(const float4*)(&xs[p1][k]);
    float xa[4] = {xa4.x, xa4.y, xa4.z, xa4.w};
    float xb[4] = {xb4.x, xb4.y, xb4.z, xb4.w};
#pragma unroll
    for (int j = 0; j < 4; ++j) {
      const float* w0r = w0 + (k + j) * HID;
      const float* swr = sw + (k + j) * HID;
      float4 wA = *(const float4*)(w0r + ca);
      float4 wB = *(const float4*)(w0r + cb);
      float4 sA = *(const float4*)(swr + ca);
      float4 sB = *(const float4*)(swr + cb);
      float ra = fmaxf(xa[j], 0.f), rb = fmaxf(xb[j], 0.f);
      fma4(accy + 0, ra, wA);
      fma4(accy + 4, ra, wB);
      fma4(accy + 8, rb, wA);
      fma4(accy + 12, rb, wB);
      fma4(acco + 0, xa[j], sA);
      fma4(acco + 4, xa[j], sB);
      fma4(acco + 8, xb[j], sA);
      fma4(acco + 12, xb[j], sB);
    }
  }
  __syncthreads();  // all reads of xs done; reuse it for h
  {
    float4 bA = *(const float4*)(b0 + ca);
    float4 bB = *(const float4*)(b0 + cb);
    float4 h;
    h.x = fmaxf(accy[0] + bA.x, 0.f);
    h.y = fmaxf(accy[1] + bA.y, 0.f);
    h.z = fmaxf(accy[2] + bA.z, 0.f);
    h.w = fmaxf(accy[3] + bA.w, 0.f);
    *(float4*)(&xs[p0][ca]) = h;
    h.x = fmaxf(accy[4] + bB.x, 0.f);
    h.y = fmaxf(accy[5] + bB.y, 0.f);
    h.z = fmaxf(accy[6] + bB.z, 0.f);
    h.w = fmaxf(accy[7] + bB.w, 0.f);
    *(float4*)(&xs[p0][cb]) = h;
    h.x = fmaxf(accy[8] + bA.x, 0.f);
    h.y = fmaxf(accy[9] + bA.y, 0.f);
    h.z = fmaxf(accy[10] + bA.z, 0.f);
    h.w = fmaxf(accy[11] + bA.w, 0.f);
    *(float4*)(&xs[p1][ca]) = h;
    h.x = fmaxf(accy[12] + bB.x, 0.f);
    h.y = fmaxf(accy[13] + bB.y, 0.f);
    h.z = fmaxf(accy[14] + bB.z, 0.f);
    h.w = fmaxf(accy[15] + bB.w, 0.f);
    *(float4*)(&xs[p1][cb]) = h;
  }
  __syncthreads();

  // GEMM2: acco += h @ w1, K=128
  for (int k = 0; k < HID; k += 4) {
    float4 ha4 = *(const float4*)(&xs[p0][k]);
    float4 hb4 = *(const float4*)(&xs[p1][k]);
    float ha[4] = {ha4.x, ha4.y, ha4.z, ha4.w};
    float hb[4] = {hb4.x, hb4.y, hb4.z, hb4.w};
#pragma unroll
    for (int j = 0; j < 4; ++j) {
      const float* w1r = w1 + (k + j) * HID;
      float4 wA = *(const float4*)(w1r + ca);
      float4 wB = *(const float4*)(w1r + cb);
      fma4(acco + 0, ha[j], wA);
      fma4(acco + 4, ha[j], wB);
      fma4(acco + 8, hb[j], wA);
      fma4(acco + 12, hb[j], wB);
    }
  }

  // epilogue: out = acco + b1
  {
    float4 bA = *(const float4*)(b1 + ca);
    float4 bB = *(const float4*)(b1 + cb);
    float* o0 = net_out + ((long)(b * T_PTS + t0 + p0)) * HID;
    float* o1 = net_out + ((long)(b * T_PTS + t0 + p1)) * HID;
    float4 v;
    v.x = acco[0] + bA.x; v.y = acco[1] + bA.y;
    v.z = acco[2] + bA.z; v.w = acco[3] + bA.w;
    *(float4*)(o0 + ca) = v;
    v.x = acco[4] + bB.x; v.y = acco[5] + bB.y;
    v.z = acco[6] + bB.z; v.w = acco[7] + bB.w;
    *(float4*)(o0 + cb) = v;
    v.x = acco[8] + bA.x; v.y = acco[9] + bA.y;
    v.z = acco[10] + bA.z; v.w = acco[11] + bA.w;
    *(float4*)(o1 + ca) = v;
    v.x = acco[12] + bB.x; v.y = acco[13] + bB.y;
    v.z = acco[14] + bB.z; v.w = acco[15] + bB.w;
    *(float4*)(o1 + cb) = v;
  }
}

// c = net @ fc_c_w + fc_c_b, scatter-add into per-cell sums
__global__ __launch_bounds__(256, 3) void final_kernel(
    const float* __restrict__ net, const int* __restrict__ idx,
    const float* __restrict__ wc, const float* __restrict__ bc,
    float* __restrict__ sums) {
  __shared__ float xs[PTILE][132];
  const int tid = threadIdx.x;
  const int b = blockIdx.x / TPB;
  const int t0 = (blockIdx.x % TPB) * PTILE;
  {
    const int pt = tid >> 3;
    const int c0 = (tid & 7) * 16;
    const float* np = net + ((long)(b * T_PTS + t0 + pt)) * HID;
#pragma unroll
    for (int j = 0; j < 16; j += 4)
      *(float4*)(&xs[pt][c0 + j]) = *(const float4*)(np + c0 + j);
  }
  __syncthreads();

  const int pc = tid & 15;
  const int pr = tid >> 4;
  const int p0 = pr * 2, p1 = p0 + 1;
  const int ca = pc * 4, cb = 64 + pc * 4;
  float acc[16];
#pragma unroll
  for (int i = 0; i < 16; ++i) acc[i] = 0.f;

  for (int k = 0; k < HID; k += 4) {
    float4 xa4 = *(const float4*)(&xs[p0][k]);
    float4 xb4 = *(const float4*)(&xs[p1][k]);
    float xa[4] = {xa4.x, xa4.y, xa4.z, xa4.w};
    float xb[4] = {xb4.x, xb4.y, xb4.z, xb4.w};
#pragma unroll
    for (int j = 0; j < 4; ++j) {
      const float* wr = wc + (k + j) * HID;
      float4 wA = *(const float4*)(wr + ca);
      float4 wB = *(const float4*)(wr + cb);
      fma4(acc + 0, xa[j], wA);
      fma4(acc + 4, xa[j], wB);
      fma4(acc + 8, xb[j], wA);
      fma4(acc + 12, xb[j], wB);
    }
  }
  const float4 bA = *(const float4*)(bc + ca);
  const float4 bB = *(const float4*)(bc + cb);
  const int g0 = idx[(long)(b * T_PTS + t0 + p0)];
  const int g1 = idx[(long)(b * T_PTS + t0 + p1)];
  float* s0 = sums + ((long)(b * GCELLS + g0)) * HID;
  float* s1 = sums + ((long)(b * GCELLS + g1)) * HID;
  atomicAdd(s0 + ca + 0, acc[0] + bA.x);
  atomicAdd(s0 + ca + 1, acc[1] + bA.y);
  atomicAdd(s0 + ca + 2, acc[2] + bA.z);
  atomicAdd(s0 + ca + 3, acc[3] + bA.w);
  atomicAdd(s0 + cb + 0, acc[4] + bB.x);
  atomicAdd(s0 + cb + 1, acc[5] + bB.y);
  atomicAdd(s0 + cb + 2, acc[6] + bB.z);
  atomicAdd(s0 + cb + 3, acc[7] + bB.w);
  atomicAdd(s1 + ca + 0, acc[8] + bA.x);
  atomicAdd(s1 + ca + 1, acc[9] + bA.y);
  atomicAdd(s1 + ca + 2, acc[10] + bA.z);
  atomicAdd(s1 + ca + 3, acc[11] + bA.w);
  atomicAdd(s1 + cb + 0, acc[12] + bB.x);
  atomicAdd(s1 + cb + 1, acc[13] + bB.y);
  atomicAdd(s1 + cb + 2, acc[14] + bB.z);
  atomicAdd(s1 + cb + 3, acc[15] + bB.w);
}

__global__ void pool_scatter_kernel(const float* __restrict__ net,
                                    const int* __restrict__ idx,
                                    unsigned* __restrict__ cell) {
  const int gid = blockIdx.x * 256 + threadIdx.x;  // one float4 per thread
  if (gid >= NB * T_PTS * (HID / 4)) return;
  const int pt = gid >> 5;
  const int c4 = (gid & 31) * 4;
  const int b = pt / T_PTS;
  const int g = idx[pt];
  float4 v = *(const float4*)(net + (long)pt * HID + c4);
  unsigned* cp = cell + ((long)(b * GCELLS + g)) * HID + c4;
  atomicMax(cp + 0, enc_f(v.x));
  atomicMax(cp + 1, enc_f(v.y));
  atomicMax(cp + 2, enc_f(v.z));
  atomicMax(cp + 3, enc_f(v.w));
}

__global__ void count_kernel(const int* __restrict__ idx,
                             float* __restrict__ cnts) {
  const int gid = blockIdx.x * 256 + threadIdx.x;
  if (gid >= NB * T_PTS) return;
  const int b = gid / T_PTS;
  atomicAdd(&cnts[b * GCELLS + idx[gid]], 1.0f);
}

__global__ void fill_u32_kernel(unsigned* __restrict__ p, unsigned v, int n4) {
  const int i = blockIdx.x * 256 + threadIdx.x;
  if (i >= n4) return;
  uint4 q; q.x = v; q.y = v; q.z = v; q.w = v;
  *(uint4*)(p + (long)i * 4) = q;
}

__global__ void mean_kernel(const float* __restrict__ sums,
                            const float* __restrict__ cnts,
                            float* __restrict__ out) {
  const long gid = (long)blockIdx.x * 256 + threadIdx.x;
  if (gid >= (long)NB * HID * GCELLS) return;
  const int g = (int)(gid % GCELLS);
  const int c = (int)((gid / GCELLS) % HID);
  const int b = (int)(gid / ((long)HID * GCELLS));
  const float cnt = cnts[b * GCELLS + g];
  const float s = sums[((long)(b * GCELLS + g)) * HID + c];
  out[gid] = cnt > 0.f ? s / cnt : 0.f;
}

extern "C" void kernel_launch(void* const* d_in, const int* in_sizes, int n_in,
                              void* d_out, int out_size, void* d_ws,
                              size_t ws_size, hipStream_t stream) {
  const float* points = (const float*)d_in[0];
  const int* idx = (const int*)d_in[1];
  const float* fc_pos_w = (const float*)d_in[2];
  const float* fc_pos_b = (const float*)d_in[3];
  const float* fc0_w = (const float*)d_in[4];
  const float* fc0_b = (const float*)d_in[5];
  const float* fc1_w = (const float*)d_in[6];
  const float* fc1_b = (const float*)d_in[7];
  const float* sc_w = (const float*)d_in[8];
  const float* fc_c_w = (const float*)d_in[9];
  const float* fc_c_b = (const float*)d_in[10];
  float* out = (float*)d_out;

  const long NET_BYTES = (long)NB * T_PTS * HID * 4;   // 102,400,000
  const long CELL_BYTES = (long)NB * GCELLS * HID * 4; // 33,554,432
  float* net = (float*)d_ws;
  unsigned* cell = (unsigned*)((char*)d_ws + NET_BYTES);
  float* sums = (float*)cell;  // reused after last pooling
  float* cnts = (float*)((char*)d_ws + NET_BYTES + CELL_BYTES);

  const int GRID_RB = NB * TPB;                       // 6250
  const int GRID_SCAT = NB * T_PTS * (HID / 4) / 256; // 25000
  const int CELL_N4 = NB * GCELLS * HID / 4;          // 2,097,152
  const int GRID_FILLC = CELL_N4 / 256;               // 8192
  const int CNT_N4 = NB * GCELLS / 4;                 // 16384
  const int GRID_FILLN = CNT_N4 / 256;                // 64
  const int GRID_CNT = (NB * T_PTS + 255) / 256;      // 782
  const int GRID_MEAN = NB * HID * GCELLS / 256;      // 32768

  // block 0 (pos encoding fused)
  resblock_kernel<0><<<GRID_RB, 256, 0, stream>>>(
      points, fc_pos_w, fc_pos_b, nullptr, nullptr, fc0_w, fc0_b, fc1_w, fc1_b,
      sc_w, net);

  for (int i = 1; i < 5; ++i) {
    fill_u32_kernel<<<GRID_FILLC, 256, 0, stream>>>(cell, 0x007FFFFFu,
                                                    CELL_N4);  // enc(-inf)
    pool_scatter_kernel<<<GRID_SCAT, 256, 0, stream>>>(net, idx, cell);
    resblock_kernel<1><<<GRID_RB, 256, 0, stream>>>(
        net, nullptr, nullptr, cell, idx, fc0_w + (long)i * KD * HID,
        fc0_b + i * HID, fc1_w + (long)i * HID * HID, fc1_b + i * HID,
        sc_w + (long)i * KD * HID, net);
  }

  // sums (reuse cell buffer) and counts
  fill_u32_kernel<<<GRID_FILLC, 256, 0, stream>>>((unsigned*)sums, 0u, CELL_N4);
  fill_u32_kernel<<<GRID_FILLN, 256, 0, stream>>>((unsigned*)cnts, 0u, CNT_N4);
  count_kernel<<<GRID_CNT, 256, 0, stream>>>(idx, cnts);
  final_kernel<<<GRID_RB, 256, 0, stream>>>(net, idx, fc_c_w, fc_c_b, sums);
  mean_kernel<<<GRID_MEAN, 256, 0, stream>>>(sums, cnts, out);
}

// Round 2
// 1857.379 us; speedup vs baseline: 3.3124x; 3.3124x over previous
//
#include <hip/hip_runtime.h>

#define T_PTS 100000
#define NB 2
#define GCELLS 32768
#define HID 128
#define MBLK 128
#define RBPB 782                 /* ceil(100000/128) */
#define GRID_RB (NB * RBPB)

typedef __attribute__((ext_vector_type(8))) short bf16x8;
typedef __attribute__((ext_vector_type(4))) float f32x4;

#define MFMA16 __builtin_amdgcn_mfma_f32_16x16x32_bf16

__device__ __forceinline__ unsigned enc_f(float f) {
  unsigned u = __float_as_uint(f);
  return (u & 0x80000000u) ? ~u : (u | 0x80000000u);
}
__device__ __forceinline__ float dec_f(unsigned e) {
  return __uint_as_float((e & 0x80000000u) ? (e & 0x7FFFFFFFu) : ~e);
}
__device__ __forceinline__ unsigned short bf16rne(float f) {
  unsigned u = __float_as_uint(f);
  return (unsigned short)((u + 0x7FFFu + ((u >> 16) & 1u)) >> 16);
}

// ---------------------------------------------------------------------------
// Fused resnet block, MFMA bf16x2 (3-pass). 128 points/block, 4 waves (2x2),
// each wave: 64 rows x 64 cols as 4x4 tiles of 16x16x32.
// LDS: abuf[2 slots][4 planes: xh,xl,rh,rl][8 mt][64 lane][8] bf16 = 64 KB.
// After GEMM1+3, same LDS holds hpack[2 planes][4 ks2][8 mt][64][8].
// ---------------------------------------------------------------------------
template <int MODE>
__global__ __launch_bounds__(256, 2) void resblock_mfma(
    const float* __restrict__ src, const float* __restrict__ posw,
    const float* __restrict__ posb, const unsigned* __restrict__ cell,
    const int* __restrict__ idx, const unsigned short* __restrict__ w0p,
    const float* __restrict__ b0, const unsigned short* __restrict__ w1p,
    const float* __restrict__ b1, const unsigned short* __restrict__ swp,
    float* __restrict__ net_out) {
  extern __shared__ unsigned short lds[];
  const int tid = threadIdx.x;
  const int lane = tid & 63;
  const int wid = tid >> 6;
  const int wr = wid >> 1, wc = wid & 1;
  const int b = blockIdx.x / RBPB;
  const int t0 = (blockIdx.x % RBPB) * MBLK;
  const int valid = (T_PTS - t0 < MBLK) ? (T_PTS - t0) : MBLK;

  f32x4 accy[4][4], acco[4][4];
#pragma unroll
  for (int i = 0; i < 4; ++i)
#pragma unroll
    for (int j = 0; j < 4; ++j) {
      f32x4 z = {0.f, 0.f, 0.f, 0.f};
      accy[i][j] = z;
      acco[i][j] = z;
    }

  auto stage = [&](int ks) {
    const int slot = ks & 1;
    const int pt = tid >> 1;
    const int kc = (tid & 1) << 4;
    float xv[16];
    if (MODE == 0) {
      float p0 = 0.f, p1 = 0.f, p2 = 0.f;
      if (pt < valid) {
        const float* pp = src + ((long)b * T_PTS + t0 + pt) * 3;
        p0 = pp[0]; p1 = pp[1]; p2 = pp[2];
      }
      const int kb = ks * 32 + kc;
#pragma unroll
      for (int i = 0; i < 16; i += 4) {
        float4 wa = *(const float4*)(posw + kb + i);
        float4 wb = *(const float4*)(posw + 256 + kb + i);
        float4 wcc = *(const float4*)(posw + 512 + kb + i);
        float4 bb = *(const float4*)(posb + kb + i);
        xv[i + 0] = fmaf(p0, wa.x, fmaf(p1, wb.x, fmaf(p2, wcc.x, bb.x)));
        xv[i + 1] = fmaf(p0, wa.y, fmaf(p1, wb.y, fmaf(p2, wcc.y, bb.y)));
        xv[i + 2] = fmaf(p0, wa.z, fmaf(p1, wb.z, fmaf(p2, wcc.z, bb.z)));
        xv[i + 3] = fmaf(p0, wa.w, fmaf(p1, wb.w, fmaf(p2, wcc.w, bb.w)));
      }
    } else {
      if (pt < valid) {
        if (ks < 4) {
          const float* np =
              src + ((long)b * T_PTS + t0 + pt) * HID + ks * 32 + kc;
#pragma unroll
          for (int i = 0; i < 16; i += 4) {
            float4 v = *(const float4*)(np + i);
            xv[i] = v.x; xv[i + 1] = v.y; xv[i + 2] = v.z; xv[i + 3] = v.w;
          }
        } else {
          const int g = idx[(long)b * T_PTS + t0 + pt];
          const unsigned* cp =
              cell + ((long)b * GCELLS + g) * HID + (ks - 4) * 32 + kc;
#pragma unroll
          for (int i = 0; i < 16; i += 4) {
            uint4 e = *(const uint4*)(cp + i);
            xv[i] = dec_f(e.x); xv[i + 1] = dec_f(e.y);
            xv[i + 2] = dec_f(e.z); xv[i + 3] = dec_f(e.w);
          }
        }
      } else {
#pragma unroll
        for (int i = 0; i < 16; ++i) xv[i] = 0.f;
      }
    }
#pragma unroll
    for (int run = 0; run < 2; ++run) {
      bf16x8 vh, vl, vrh, vrl;
#pragma unroll
      for (int i = 0; i < 8; ++i) {
        float x = xv[run * 8 + i];
        unsigned short h = bf16rne(x);
        float hf = __uint_as_float(((unsigned)h) << 16);
        unsigned short lo = bf16rne(x - hf);
        bool pos = x > 0.f;
        vh[i] = (short)h;
        vl[i] = (short)lo;
        vrh[i] = pos ? (short)h : (short)0;
        vrl[i] = pos ? (short)lo : (short)0;
      }
      const int l = ((kc >> 3) + run) * 16 + (pt & 15);
      const int base = slot * 16384 + (pt >> 4) * 512 + l * 8;
      *(bf16x8*)(lds + base) = vh;
      *(bf16x8*)(lds + base + 4096) = vl;
      *(bf16x8*)(lds + base + 8192) = vrh;
      *(bf16x8*)(lds + base + 12288) = vrl;
    }
  };

  stage(0);
  __syncthreads();

#pragma unroll 1
  for (int ks = 0; ks < 8; ++ks) {
    if (ks < 7) stage(ks + 1);
    const int slot = ks & 1;
    bf16x8 b0h[4], b0l[4], bsh[4], bsl[4];
#pragma unroll
    for (int nt = 0; nt < 4; ++nt) {
      const int fi = (ks * 8 + wc * 4 + nt) * 512 + lane * 8;
      b0h[nt] = *(const bf16x8*)(w0p + fi);
      b0l[nt] = *(const bf16x8*)(w0p + 32768 + fi);
      bsh[nt] = *(const bf16x8*)(swp + fi);
      bsl[nt] = *(const bf16x8*)(swp + 32768 + fi);
    }
#pragma unroll
    for (int mt = 0; mt < 4; ++mt) {
      const int ab = slot * 16384 + (wr * 4 + mt) * 512 + lane * 8;
      bf16x8 axh = *(const bf16x8*)(lds + ab);
      bf16x8 axl = *(const bf16x8*)(lds + ab + 4096);
      bf16x8 arh = *(const bf16x8*)(lds + ab + 8192);
      bf16x8 arl = *(const bf16x8*)(lds + ab + 12288);
#pragma unroll
      for (int nt = 0; nt < 4; ++nt) {
        accy[mt][nt] = MFMA16(arh, b0h[nt], accy[mt][nt], 0, 0, 0);
        accy[mt][nt] = MFMA16(arh, b0l[nt], accy[mt][nt], 0, 0, 0);
        accy[mt][nt] = MFMA16(arl, b0h[nt], accy[mt][nt], 0, 0, 0);
        acco[mt][nt] = MFMA16(axh, bsh[nt], acco[mt][nt], 0, 0, 0);
        acco[mt][nt] = MFMA16(axh, bsl[nt], acco[mt][nt], 0, 0, 0);
        acco[mt][nt] = MFMA16(axl, bsh[nt], acco[mt][nt], 0, 0, 0);
      }
    }
    __syncthreads();
  }

  // h = relu(y + b0) -> hpack in LDS (aliases abuf)
  {
    float b0v[4];
#pragma unroll
    for (int nt = 0; nt < 4; ++nt) b0v[nt] = b0[wc * 64 + nt * 16 + (lane & 15)];
#pragma unroll
    for (int mt = 0; mt < 4; ++mt) {
      const int mt2 = wr * 4 + mt;
#pragma unroll
      for (int nt = 0; nt < 4; ++nt) {
        const int colk = wc * 64 + nt * 16 + (lane & 15);
        const int k2 = colk >> 5;
        const int lg = (colk >> 3) & 3;
        const int j = colk & 7;
#pragma unroll
        for (int r = 0; r < 4; ++r) {
          float h = fmaxf(accy[mt][nt][r] + b0v[nt], 0.f);
          unsigned short hh = bf16rne(h);
          float hf = __uint_as_float(((unsigned)hh) << 16);
          unsigned short hl = bf16rne(h - hf);
          const int l2 = lg * 16 + (lane >> 4) * 4 + r;
          const int o = k2 * 4096 + mt2 * 512 + l2 * 8 + j;
          lds[o] = hh;
          lds[o + 16384] = hl;
        }
      }
    }
  }
  __syncthreads();

  // GEMM2: acco += h @ w1
#pragma unroll
  for (int k2 = 0; k2 < 4; ++k2) {
    bf16x8 bh[4], bl[4];
#pragma unroll
    for (int nt = 0; nt < 4; ++nt) {
      const int fi = (k2 * 8 + wc * 4 + nt) * 512 + lane * 8;
      bh[nt] = *(const bf16x8*)(w1p + fi);
      bl[nt] = *(const bf16x8*)(w1p + 16384 + fi);
    }
#pragma unroll
    for (int mt = 0; mt < 4; ++mt) {
      const int ab = k2 * 4096 + (wr * 4 + mt) * 512 + lane * 8;
      bf16x8 ah = *(const bf16x8*)(lds + ab);
      bf16x8 al = *(const bf16x8*)(lds + ab + 16384);
#pragma unroll
      for (int nt = 0; nt < 4; ++nt) {
        acco[mt][nt] = MFMA16(ah, bh[nt], acco[mt][nt], 0, 0, 0);
        acco[mt][nt] = MFMA16(ah, bl[nt], acco[mt][nt], 0, 0, 0);
        acco[mt][nt] = MFMA16(al, bh[nt], acco[mt][nt], 0, 0, 0);
      }
    }
  }

  // epilogue: out = acco + b1
  {
    float b1v[4];
#pragma unroll
    for (int nt = 0; nt < 4; ++nt) b1v[nt] = b1[wc * 64 + nt * 16 + (lane & 15)];
#pragma unroll
    for (int mt = 0; mt < 4; ++mt) {
#pragma unroll
      for (int r = 0; r < 4; ++r) {
        const int row = wr * 64 + mt * 16 + (lane >> 4) * 4 + r;
        if (row < valid) {
          float* op = net_out + ((long)b * T_PTS + t0 + row) * HID;
#pragma unroll
          for (int nt = 0; nt < 4; ++nt)
            op[wc * 64 + nt * 16 + (lane & 15)] = acco[mt][nt][r] + b1v[nt];
        }
      }
    }
  }
}

// ---------------------------------------------------------------------------
// final: c = net @ fc_c_w + fc_c_b, scatter-add into per-cell sums. K=128.
// ---------------------------------------------------------------------------
__global__ __launch_bounds__(256, 2) void final_mfma(
    const float* __restrict__ net, const int* __restrict__ idx,
    const unsigned short* __restrict__ wcp, const float* __restrict__ bc,
    float* __restrict__ sums) {
  extern __shared__ unsigned short lds[];
  const int tid = threadIdx.x;
  const int lane = tid & 63;
  const int wid = tid >> 6;
  const int wr = wid >> 1, wc = wid & 1;
  const int b = blockIdx.x / RBPB;
  const int t0 = (blockIdx.x % RBPB) * MBLK;
  const int valid = (T_PTS - t0 < MBLK) ? (T_PTS - t0) : MBLK;

  f32x4 acc[4][4];
#pragma unroll
  for (int i = 0; i < 4; ++i)
#pragma unroll
    for (int j = 0; j < 4; ++j) {
      f32x4 z = {0.f, 0.f, 0.f, 0.f};
      acc[i][j] = z;
    }

  auto stage = [&](int ks) {
    const int slot = ks & 1;
    const int pt = tid >> 1;
    const int kc = (tid & 1) << 4;
    float xv[16];
    if (pt < valid) {
      const float* np = net + ((long)b * T_PTS + t0 + pt) * HID + ks * 32 + kc;
#pragma unroll
      for (int i = 0; i < 16; i += 4) {
        float4 v = *(const float4*)(np + i);
        xv[i] = v.x; xv[i + 1] = v.y; xv[i + 2] = v.z; xv[i + 3] = v.w;
      }
    } else {
#pragma unroll
      for (int i = 0; i < 16; ++i) xv[i] = 0.f;
    }
#pragma unroll
    for (int run = 0; run < 2; ++run) {
      bf16x8 vh, vl;
#pragma unroll
      for (int i = 0; i < 8; ++i) {
        float x = xv[run * 8 + i];
        unsigned short h = bf16rne(x);
        float hf = __uint_as_float(((unsigned)h) << 16);
        unsigned short lo = bf16rne(x - hf);
        vh[i] = (short)h;
        vl[i] = (short)lo;
      }
      const int l = ((kc >> 3) + run) * 16 + (pt & 15);
      const int base = slot * 8192 + (pt >> 4) * 512 + l * 8;
      *(bf16x8*)(lds + base) = vh;
      *(bf16x8*)(lds + base + 4096) = vl;
    }
  };

  stage(0);
  __syncthreads();
#pragma unroll 1
  for (int ks = 0; ks < 4; ++ks) {
    if (ks < 3) stage(ks + 1);
    const int slot = ks & 1;
    bf16x8 bh[4], bl[4];
#pragma unroll
    for (int nt = 0; nt < 4; ++nt) {
      const int fi = (ks * 8 + wc * 4 + nt) * 512 + lane * 8;
      bh[nt] = *(const bf16x8*)(wcp + fi);
      bl[nt] = *(const bf16x8*)(wcp + 16384 + fi);
    }
#pragma unroll
    for (int mt = 0; mt < 4; ++mt) {
      const int ab = slot * 8192 + (wr * 4 + mt) * 512 + lane * 8;
      bf16x8 ah = *(const bf16x8*)(lds + ab);
      bf16x8 al = *(const bf16x8*)(lds + ab + 4096);
#pragma unroll
      for (int nt = 0; nt < 4; ++nt) {
        acc[mt][nt] = MFMA16(ah, bh[nt], acc[mt][nt], 0, 0, 0);
        acc[mt][nt] = MFMA16(ah, bl[nt], acc[mt][nt], 0, 0, 0);
        acc[mt][nt] = MFMA16(al, bh[nt], acc[mt][nt], 0, 0, 0);
      }
    }
    __syncthreads();
  }

  float bcv[4];
#pragma unroll
  for (int nt = 0; nt < 4; ++nt) bcv[nt] = bc[wc * 64 + nt * 16 + (lane & 15)];
#pragma unroll
  for (int mt = 0; mt < 4; ++mt) {
#pragma unroll
    for (int r = 0; r < 4; ++r) {
      const int row = wr * 64 + mt * 16 + (lane >> 4) * 4 + r;
      if (row < valid) {
        const int g = idx[(long)b * T_PTS + t0 + row];
        float* sp = sums + ((long)b * GCELLS + g) * HID;
#pragma unroll
        for (int nt = 0; nt < 4; ++nt)
          atomicAdd(sp + wc * 64 + nt * 16 + (lane & 15),
                    acc[mt][nt][r] + bcv[nt]);
      }
    }
  }
}

// ---------------------------------------------------------------------------
// one-time weight pack: fp32 (K,128) -> bf16 hi/lo planes in MFMA-B-frag order
// frag (ks,nt): lane l, elem j <-> W[ks*32 + (l>>4)*8 + j][nt*16 + (l&15)]
// ---------------------------------------------------------------------------
__global__ void pack_weights(const float* __restrict__ fc0,
                             const float* __restrict__ fc1,
                             const float* __restrict__ sc,
                             const float* __restrict__ fcc,
                             unsigned short* __restrict__ w0p,
                             unsigned short* __restrict__ w1p,
                             unsigned short* __restrict__ swp,
                             unsigned short* __restrict__ wcp) {
  int gid = blockIdx.x * 256 + threadIdx.x;
  const float* src;
  unsigned short* dst;
  int K, e;
  if (gid < 163840) { src = fc0; dst = w0p; K = 256; e = gid; }
  else if (gid < 327680) { src = sc; dst = swp; K = 256; e = gid - 163840; }
  else if (gid < 409600) { src = fc1; dst = w1p; K = 128; e = gid - 327680; }
  else if (gid < 425984) { src = fcc; dst = wcp; K = 128; e = gid - 409600; }
  else return;
  const int mat = e / (K * 128);
  const int r = e - mat * K * 128;
  const int k = r >> 7, n = r & 127;
  const float x = src[e];
  const unsigned short hi = bf16rne(x);
  const float hf = __uint_as_float(((unsigned)hi) << 16);
  const unsigned short lo = bf16rne(x - hf);
  const int ks = k >> 5, lg = (k >> 3) & 3, j = k & 7;
  const int l = lg * 16 + (n & 15), nt = n >> 4;
  unsigned short* mb = dst + (long)mat * K * 256;
  const int off = ((ks * 8 + nt) * 64 + l) * 8 + j;
  mb[off] = hi;
  mb[off + K * 128] = lo;
}

// --------------------------- pooling / misc --------------------------------
__global__ void pool_scatter_kernel(const float* __restrict__ net,
                                    const int* __restrict__ idx,
                                    unsigned* __restrict__ cell) {
  const int gid = blockIdx.x * 256 + threadIdx.x;
  if (gid >= NB * T_PTS * (HID / 4)) return;
  const int pt = gid >> 5;
  const int c4 = (gid & 31) * 4;
  const int b = pt / T_PTS;
  const int g = idx[pt];
  float4 v = *(const float4*)(net + (long)pt * HID + c4);
  unsigned* cp = cell + ((long)(b * GCELLS + g)) * HID + c4;
  atomicMax(cp + 0, enc_f(v.x));
  atomicMax(cp + 1, enc_f(v.y));
  atomicMax(cp + 2, enc_f(v.z));
  atomicMax(cp + 3, enc_f(v.w));
}

__global__ void count_kernel(const int* __restrict__ idx,
                             float* __restrict__ cnts) {
  const int gid = blockIdx.x * 256 + threadIdx.x;
  if (gid >= NB * T_PTS) return;
  const int b = gid / T_PTS;
  atomicAdd(&cnts[b * GCELLS + idx[gid]], 1.0f);
}

__global__ void fill_u32_kernel(unsigned* __restrict__ p, unsigned v, int n4) {
  const int i = blockIdx.x * 256 + threadIdx.x;
  if (i >= n4) return;
  uint4 q; q.x = v; q.y = v; q.z = v; q.w = v;
  *(uint4*)(p + (long)i * 4) = q;
}

__global__ void mean_kernel(const float* __restrict__ sums,
                            const float* __restrict__ cnts,
                            float* __restrict__ out) {
  const long gid = (long)blockIdx.x * 256 + threadIdx.x;
  if (gid >= (long)NB * HID * GCELLS) return;
  const int g = (int)(gid % GCELLS);
  const int c = (int)((gid / GCELLS) % HID);
  const int b = (int)(gid / ((long)HID * GCELLS));
  const float cnt = cnts[b * GCELLS + g];
  const float s = sums[((long)(b * GCELLS + g)) * HID + c];
  out[gid] = cnt > 0.f ? s / cnt : 0.f;
}

extern "C" void kernel_launch(void* const* d_in, const int* in_sizes, int n_in,
                              void* d_out, int out_size, void* d_ws,
                              size_t ws_size, hipStream_t stream) {
  const float* points = (const float*)d_in[0];
  const int* idx = (const int*)d_in[1];
  const float* fc_pos_w = (const float*)d_in[2];
  const float* fc_pos_b = (const float*)d_in[3];
  const float* fc0_w = (const float*)d_in[4];
  const float* fc0_b = (const float*)d_in[5];
  const float* fc1_w = (const float*)d_in[6];
  const float* fc1_b = (const float*)d_in[7];
  const float* sc_w = (const float*)d_in[8];
  const float* fc_c_w = (const float*)d_in[9];
  const float* fc_c_b = (const float*)d_in[10];
  float* out = (float*)d_out;

  const long NET_BYTES = (long)NB * T_PTS * HID * 4;    // 102,400,000
  const long CELL_BYTES = (long)NB * GCELLS * HID * 4;  // 33,554,432
  float* net = (float*)d_ws;
  unsigned* cell = (unsigned*)((char*)d_ws + NET_BYTES);
  float* sums = (float*)cell;  // reused after last pooling
  float* cnts = (float*)((char*)d_ws + NET_BYTES + CELL_BYTES);

  // weight packs live in d_out scratch (1.7 MB); mean_kernel overwrites later
  unsigned short* packs = (unsigned short*)d_out;
  unsigned short* w0p = packs;            // 5 * 65536
  unsigned short* swp = packs + 327680;   // 5 * 65536
  unsigned short* w1p = packs + 655360;   // 5 * 32768
  unsigned short* wcp = packs + 819200;   // 32768

  const int GRID_SCAT = NB * T_PTS * (HID / 4) / 256;  // 25000
  const int CELL_N4 = NB * GCELLS * HID / 4;           // 2,097,152
  const int GRID_FILLC = CELL_N4 / 256;                // 8192
  const int CNT_N4 = NB * GCELLS / 4;                  // 16384
  const int GRID_FILLN = CNT_N4 / 256;                 // 64
  const int GRID_CNT = (NB * T_PTS + 255) / 256;       // 782
  const int GRID_MEAN = NB * HID * GCELLS / 256;       // 32768

  pack_weights<<<1664, 256, 0, stream>>>(fc0_w, fc1_w, sc_w, fc_c_w, w0p, w1p,
                                         swp, wcp);

  resblock_mfma<0><<<GRID_RB, 256, 65536, stream>>>(
      points, fc_pos_w, fc_pos_b, nullptr, nullptr, w0p, fc0_b, w1p, fc1_b,
      swp, net);

  for (int i = 1; i < 5; ++i) {
    fill_u32_kernel<<<GRID_FILLC, 256, 0, stream>>>(cell, 0x007FFFFFu,
                                                    CELL_N4);  // enc(-inf)
    pool_scatter_kernel<<<GRID_SCAT, 256, 0, stream>>>(net, idx, cell);
    resblock_mfma<1><<<GRID_RB, 256, 65536, stream>>>(
        net, nullptr, nullptr, cell, idx, w0p + (long)i * 65536,
        fc0_b + i * HID, w1p + (long)i * 32768, fc1_b + i * HID,
        swp + (long)i * 65536, net);
  }

  fill_u32_kernel<<<GRID_FILLC, 256, 0, stream>>>((unsigned*)sums, 0u, CELL_N4);
  fill_u32_kernel<<<GRID_FILLN, 256, 0, stream>>>((unsigned*)cnts, 0u, CNT_N4);
  count_kernel<<<GRID_CNT, 256, 0, stream>>>(idx, cnts);
  final_mfma<<<GRID_RB, 256, 32768, stream>>>(net, idx, wcp, fc_c_b, sums);
  mean_kernel<<<GRID_MEAN, 256, 0, stream>>>(sums, cnts, out);
}

// Round 3
// 865.280 us; speedup vs baseline: 7.1103x; 2.1466x over previous
//
#include <hip/hip_runtime.h>

#define T_PTS 100000
#define NB 2
#define GCELLS 32768
#define NCELL (NB * GCELLS)
#define HID 128
#define MBLK 128
#define RBPB 782                 /* ceil(100000/128) */
#define GRID_RB (NB * RBPB)

typedef __attribute__((ext_vector_type(8))) short bf16x8;
typedef __attribute__((ext_vector_type(4))) float f32x4;

#define MFMA16 __builtin_amdgcn_mfma_f32_16x16x32_bf16

__device__ __forceinline__ unsigned short bf16rne(float f) {
  unsigned u = __float_as_uint(f);
  return (unsigned short)((u + 0x7FFFu + ((u >> 16) & 1u)) >> 16);
}

// ---------------------------------------------------------------------------
// Fused resnet block, MFMA bf16x2 (3-pass). 128 points/block, 4 waves (2x2),
// each wave: 64 rows x 64 cols as 4x4 tiles of 16x16x32.
// ---------------------------------------------------------------------------
template <int MODE>
__global__ __launch_bounds__(256, 2) void resblock_mfma(
    const float* __restrict__ src, const float* __restrict__ posw,
    const float* __restrict__ posb, const float* __restrict__ cell,
    const int* __restrict__ idx, const unsigned short* __restrict__ w0p,
    const float* __restrict__ b0, const unsigned short* __restrict__ w1p,
    const float* __restrict__ b1, const unsigned short* __restrict__ swp,
    float* __restrict__ net_out) {
  extern __shared__ unsigned short lds[];
  const int tid = threadIdx.x;
  const int lane = tid & 63;
  const int wid = tid >> 6;
  const int wr = wid >> 1, wc = wid & 1;
  const int b = blockIdx.x / RBPB;
  const int t0 = (blockIdx.x % RBPB) * MBLK;
  const int valid = (T_PTS - t0 < MBLK) ? (T_PTS - t0) : MBLK;

  f32x4 accy[4][4], acco[4][4];
#pragma unroll
  for (int i = 0; i < 4; ++i)
#pragma unroll
    for (int j = 0; j < 4; ++j) {
      f32x4 z = {0.f, 0.f, 0.f, 0.f};
      accy[i][j] = z;
      acco[i][j] = z;
    }

  auto stage = [&](int ks) {
    const int slot = ks & 1;
    const int pt = tid >> 1;
    const int kc = (tid & 1) << 4;
    float xv[16];
    if (MODE == 0) {
      float p0 = 0.f, p1 = 0.f, p2 = 0.f;
      if (pt < valid) {
        const float* pp = src + ((long)b * T_PTS + t0 + pt) * 3;
        p0 = pp[0]; p1 = pp[1]; p2 = pp[2];
      }
      const int kb = ks * 32 + kc;
#pragma unroll
      for (int i = 0; i < 16; i += 4) {
        float4 wa = *(const float4*)(posw + kb + i);
        float4 wb = *(const float4*)(posw + 256 + kb + i);
        float4 wcc = *(const float4*)(posw + 512 + kb + i);
        float4 bb = *(const float4*)(posb + kb + i);
        xv[i + 0] = fmaf(p0, wa.x, fmaf(p1, wb.x, fmaf(p2, wcc.x, bb.x)));
        xv[i + 1] = fmaf(p0, wa.y, fmaf(p1, wb.y, fmaf(p2, wcc.y, bb.y)));
        xv[i + 2] = fmaf(p0, wa.z, fmaf(p1, wb.z, fmaf(p2, wcc.z, bb.z)));
        xv[i + 3] = fmaf(p0, wa.w, fmaf(p1, wb.w, fmaf(p2, wcc.w, bb.w)));
      }
    } else {
      if (pt < valid) {
        if (ks < 4) {
          const float* np =
              src + ((long)b * T_PTS + t0 + pt) * HID + ks * 32 + kc;
#pragma unroll
          for (int i = 0; i < 16; i += 4) {
            float4 v = *(const float4*)(np + i);
            xv[i] = v.x; xv[i + 1] = v.y; xv[i + 2] = v.z; xv[i + 3] = v.w;
          }
        } else {
          const int g = idx[(long)b * T_PTS + t0 + pt];
          const float* cp =
              cell + ((long)b * GCELLS + g) * HID + (ks - 4) * 32 + kc;
#pragma unroll
          for (int i = 0; i < 16; i += 4) {
            float4 v = *(const float4*)(cp + i);
            xv[i] = v.x; xv[i + 1] = v.y; xv[i + 2] = v.z; xv[i + 3] = v.w;
          }
        }
      } else {
#pragma unroll
        for (int i = 0; i < 16; ++i) xv[i] = 0.f;
      }
    }
#pragma unroll
    for (int run = 0; run < 2; ++run) {
      bf16x8 vh, vl, vrh, vrl;
#pragma unroll
      for (int i = 0; i < 8; ++i) {
        float x = xv[run * 8 + i];
        unsigned short h = bf16rne(x);
        float hf = __uint_as_float(((unsigned)h) << 16);
        unsigned short lo = bf16rne(x - hf);
        bool pos = x > 0.f;
        vh[i] = (short)h;
        vl[i] = (short)lo;
        vrh[i] = pos ? (short)h : (short)0;
        vrl[i] = pos ? (short)lo : (short)0;
      }
      const int l = ((kc >> 3) + run) * 16 + (pt & 15);
      const int base = slot * 16384 + (pt >> 4) * 512 + l * 8;
      *(bf16x8*)(lds + base) = vh;
      *(bf16x8*)(lds + base + 4096) = vl;
      *(bf16x8*)(lds + base + 8192) = vrh;
      *(bf16x8*)(lds + base + 12288) = vrl;
    }
  };

  stage(0);
  __syncthreads();

#pragma unroll 1
  for (int ks = 0; ks < 8; ++ks) {
    if (ks < 7) stage(ks + 1);
    const int slot = ks & 1;
    bf16x8 b0h[4], b0l[4], bsh[4], bsl[4];
#pragma unroll
    for (int nt = 0; nt < 4; ++nt) {
      const int fi = (ks * 8 + wc * 4 + nt) * 512 + lane * 8;
      b0h[nt] = *(const bf16x8*)(w0p + fi);
      b0l[nt] = *(const bf16x8*)(w0p + 32768 + fi);
      bsh[nt] = *(const bf16x8*)(swp + fi);
      bsl[nt] = *(const bf16x8*)(swp + 32768 + fi);
    }
#pragma unroll
    for (int mt = 0; mt < 4; ++mt) {
      const int ab = slot * 16384 + (wr * 4 + mt) * 512 + lane * 8;
      bf16x8 axh = *(const bf16x8*)(lds + ab);
      bf16x8 axl = *(const bf16x8*)(lds + ab + 4096);
      bf16x8 arh = *(const bf16x8*)(lds + ab + 8192);
      bf16x8 arl = *(const bf16x8*)(lds + ab + 12288);
#pragma unroll
      for (int nt = 0; nt < 4; ++nt) {
        accy[mt][nt] = MFMA16(arh, b0h[nt], accy[mt][nt], 0, 0, 0);
        accy[mt][nt] = MFMA16(arh, b0l[nt], accy[mt][nt], 0, 0, 0);
        accy[mt][nt] = MFMA16(arl, b0h[nt], accy[mt][nt], 0, 0, 0);
        acco[mt][nt] = MFMA16(axh, bsh[nt], acco[mt][nt], 0, 0, 0);
        acco[mt][nt] = MFMA16(axh, bsl[nt], acco[mt][nt], 0, 0, 0);
        acco[mt][nt] = MFMA16(axl, bsh[nt], acco[mt][nt], 0, 0, 0);
      }
    }
    __syncthreads();
  }

  // h = relu(y + b0) -> hpack in LDS (aliases abuf)
  {
    float b0v[4];
#pragma unroll
    for (int nt = 0; nt < 4; ++nt) b0v[nt] = b0[wc * 64 + nt * 16 + (lane & 15)];
#pragma unroll
    for (int mt = 0; mt < 4; ++mt) {
      const int mt2 = wr * 4 + mt;
#pragma unroll
      for (int nt = 0; nt < 4; ++nt) {
        const int colk = wc * 64 + nt * 16 + (lane & 15);
        const int k2 = colk >> 5;
        const int lg = (colk >> 3) & 3;
        const int j = colk & 7;
#pragma unroll
        for (int r = 0; r < 4; ++r) {
          float h = fmaxf(accy[mt][nt][r] + b0v[nt], 0.f);
          unsigned short hh = bf16rne(h);
          float hf = __uint_as_float(((unsigned)hh) << 16);
          unsigned short hl = bf16rne(h - hf);
          const int l2 = lg * 16 + (lane >> 4) * 4 + r;
          const int o = k2 * 4096 + mt2 * 512 + l2 * 8 + j;
          lds[o] = hh;
          lds[o + 16384] = hl;
        }
      }
    }
  }
  __syncthreads();

  // GEMM2: acco += h @ w1
#pragma unroll
  for (int k2 = 0; k2 < 4; ++k2) {
    bf16x8 bh[4], bl[4];
#pragma unroll
    for (int nt = 0; nt < 4; ++nt) {
      const int fi = (k2 * 8 + wc * 4 + nt) * 512 + lane * 8;
      bh[nt] = *(const bf16x8*)(w1p + fi);
      bl[nt] = *(const bf16x8*)(w1p + 16384 + fi);
    }
#pragma unroll
    for (int mt = 0; mt < 4; ++mt) {
      const int ab = k2 * 4096 + (wr * 4 + mt) * 512 + lane * 8;
      bf16x8 ah = *(const bf16x8*)(lds + ab);
      bf16x8 al = *(const bf16x8*)(lds + ab + 16384);
#pragma unroll
      for (int nt = 0; nt < 4; ++nt) {
        acco[mt][nt] = MFMA16(ah, bh[nt], acco[mt][nt], 0, 0, 0);
        acco[mt][nt] = MFMA16(ah, bl[nt], acco[mt][nt], 0, 0, 0);
        acco[mt][nt] = MFMA16(al, bh[nt], acco[mt][nt], 0, 0, 0);
      }
    }
  }

  // epilogue: out = acco + b1
  {
    float b1v[4];
#pragma unroll
    for (int nt = 0; nt < 4; ++nt) b1v[nt] = b1[wc * 64 + nt * 16 + (lane & 15)];
#pragma unroll
    for (int mt = 0; mt < 4; ++mt) {
#pragma unroll
      for (int r = 0; r < 4; ++r) {
        const int row = wr * 64 + mt * 16 + (lane >> 4) * 4 + r;
        if (row < valid) {
          float* op = net_out + ((long)b * T_PTS + t0 + row) * HID;
#pragma unroll
          for (int nt = 0; nt < 4; ++nt)
            op[wc * 64 + nt * 16 + (lane & 15)] = acco[mt][nt][r] + b1v[nt];
        }
      }
    }
  }
}

// ---------------------------------------------------------------------------
// final: c = net @ fc_c_w + fc_c_b, written IN-PLACE back into net rows.
// ---------------------------------------------------------------------------
__global__ __launch_bounds__(256, 2) void final_mfma(
    float* __restrict__ net, const unsigned short* __restrict__ wcp,
    const float* __restrict__ bc) {
  extern __shared__ unsigned short lds[];
  const int tid = threadIdx.x;
  const int lane = tid & 63;
  const int wid = tid >> 6;
  const int wr = wid >> 1, wc = wid & 1;
  const int b = blockIdx.x / RBPB;
  const int t0 = (blockIdx.x % RBPB) * MBLK;
  const int valid = (T_PTS - t0 < MBLK) ? (T_PTS - t0) : MBLK;

  f32x4 acc[4][4];
#pragma unroll
  for (int i = 0; i < 4; ++i)
#pragma unroll
    for (int j = 0; j < 4; ++j) {
      f32x4 z = {0.f, 0.f, 0.f, 0.f};
      acc[i][j] = z;
    }

  auto stage = [&](int ks) {
    const int slot = ks & 1;
    const int pt = tid >> 1;
    const int kc = (tid & 1) << 4;
    float xv[16];
    if (pt < valid) {
      const float* np = net + ((long)b * T_PTS + t0 + pt) * HID + ks * 32 + kc;
#pragma unroll
      for (int i = 0; i < 16; i += 4) {
        float4 v = *(const float4*)(np + i);
        xv[i] = v.x; xv[i + 1] = v.y; xv[i + 2] = v.z; xv[i + 3] = v.w;
      }
    } else {
#pragma unroll
      for (int i = 0; i < 16; ++i) xv[i] = 0.f;
    }
#pragma unroll
    for (int run = 0; run < 2; ++run) {
      bf16x8 vh, vl;
#pragma unroll
      for (int i = 0; i < 8; ++i) {
        float x = xv[run * 8 + i];
        unsigned short h = bf16rne(x);
        float hf = __uint_as_float(((unsigned)h) << 16);
        unsigned short lo = bf16rne(x - hf);
        vh[i] = (short)h;
        vl[i] = (short)lo;
      }
      const int l = ((kc >> 3) + run) * 16 + (pt & 15);
      const int base = slot * 8192 + (pt >> 4) * 512 + l * 8;
      *(bf16x8*)(lds + base) = vh;
      *(bf16x8*)(lds + base + 4096) = vl;
    }
  };

  stage(0);
  __syncthreads();
#pragma unroll 1
  for (int ks = 0; ks < 4; ++ks) {
    if (ks < 3) stage(ks + 1);
    const int slot = ks & 1;
    bf16x8 bh[4], bl[4];
#pragma unroll
    for (int nt = 0; nt < 4; ++nt) {
      const int fi = (ks * 8 + wc * 4 + nt) * 512 + lane * 8;
      bh[nt] = *(const bf16x8*)(wcp + fi);
      bl[nt] = *(const bf16x8*)(wcp + 16384 + fi);
    }
#pragma unroll
    for (int mt = 0; mt < 4; ++mt) {
      const int ab = slot * 8192 + (wr * 4 + mt) * 512 + lane * 8;
      bf16x8 ah = *(const bf16x8*)(lds + ab);
      bf16x8 al = *(const bf16x8*)(lds + ab + 4096);
#pragma unroll
      for (int nt = 0; nt < 4; ++nt) {
        acc[mt][nt] = MFMA16(ah, bh[nt], acc[mt][nt], 0, 0, 0);
        acc[mt][nt] = MFMA16(ah, bl[nt], acc[mt][nt], 0, 0, 0);
        acc[mt][nt] = MFMA16(al, bh[nt], acc[mt][nt], 0, 0, 0);
      }
    }
    __syncthreads();
  }

  float bcv[4];
#pragma unroll
  for (int nt = 0; nt < 4; ++nt) bcv[nt] = bc[wc * 64 + nt * 16 + (lane & 15)];
#pragma unroll
  for (int mt = 0; mt < 4; ++mt) {
#pragma unroll
    for (int r = 0; r < 4; ++r) {
      const int row = wr * 64 + mt * 16 + (lane >> 4) * 4 + r;
      if (row < valid) {
        float* op = net + ((long)b * T_PTS + t0 + row) * HID;
#pragma unroll
        for (int nt = 0; nt < 4; ++nt)
          op[wc * 64 + nt * 16 + (lane & 15)] = acc[mt][nt][r] + bcv[nt];
      }
    }
  }
}

// ---------------------------------------------------------------------------
// one-time weight pack: fp32 (K,128) -> bf16 hi/lo planes in MFMA-B-frag order
// ---------------------------------------------------------------------------
__global__ void pack_weights(const float* __restrict__ fc0,
                             const float* __restrict__ fc1,
                             const float* __restrict__ sc,
                             const float* __restrict__ fcc,
                             unsigned short* __restrict__ w0p,
                             unsigned short* __restrict__ w1p,
                             unsigned short* __restrict__ swp,
                             unsigned short* __restrict__ wcp) {
  int gid = blockIdx.x * 256 + threadIdx.x;
  const float* src;
  unsigned short* dst;
  int K, e;
  if (gid < 163840) { src = fc0; dst = w0p; K = 256; e = gid; }
  else if (gid < 327680) { src = sc; dst = swp; K = 256; e = gid - 163840; }
  else if (gid < 409600) { src = fc1; dst = w1p; K = 128; e = gid - 327680; }
  else if (gid < 425984) { src = fcc; dst = wcp; K = 128; e = gid - 409600; }
  else return;
  const int mat = e / (K * 128);
  const int r = e - mat * K * 128;
  const int k = r >> 7, n = r & 127;
  const float x = src[e];
  const unsigned short hi = bf16rne(x);
  const float hf = __uint_as_float(((unsigned)hi) << 16);
  const unsigned short lo = bf16rne(x - hf);
  const int ks = k >> 5, lg = (k >> 3) & 3, j = k & 7;
  const int l = lg * 16 + (n & 15), nt = n >> 4;
  unsigned short* mb = dst + (long)mat * K * 256;
  const int off = ((ks * 8 + nt) * 64 + l) * 8 + j;
  mb[off] = hi;
  mb[off + K * 128] = lo;
}

// --------------------------- CSR build -------------------------------------
__global__ void zero_i32(int* __restrict__ p, int n) {
  const int i = blockIdx.x * 256 + threadIdx.x;
  if (i < n) p[i] = 0;
}

__global__ void count_csr(const int* __restrict__ idx, int* __restrict__ curs) {
  const int gid = blockIdx.x * 256 + threadIdx.x;
  if (gid >= NB * T_PTS) return;
  const int b = gid / T_PTS;
  atomicAdd(&curs[b * GCELLS + idx[gid]], 1);
}

// single block of 1024 threads: exclusive scan of NCELL counts -> offsets
__global__ __launch_bounds__(1024) void scan_csr(const int* __restrict__ cnt,
                                                 int* __restrict__ offsets) {
  __shared__ int part[1024];
  const int t = threadIdx.x;
  const int base = t * (NCELL / 1024);
  int s = 0;
  for (int i = 0; i < NCELL / 1024; ++i) s += cnt[base + i];
  part[t] = s;
  __syncthreads();
  for (int d = 1; d < 1024; d <<= 1) {
    int v = (t >= d) ? part[t - d] : 0;
    __syncthreads();
    part[t] += v;
    __syncthreads();
  }
  int run = (t == 0) ? 0 : part[t - 1];
  for (int i = 0; i < NCELL / 1024; ++i) {
    offsets[base + i] = run;
    run += cnt[base + i];
  }
  if (t == 1023) offsets[NCELL] = run;
}

__global__ void scatter_csr(const int* __restrict__ idx,
                            const int* __restrict__ offsets,
                            int* __restrict__ curs, int* __restrict__ perm) {
  const int gid = blockIdx.x * 256 + threadIdx.x;
  if (gid >= NB * T_PTS) return;
  const int b = gid / T_PTS;
  const int cellk = b * GCELLS + idx[gid];
  const int slot = offsets[cellk] + atomicAdd(&curs[cellk], 1);
  perm[slot] = gid;
}

// ------------------- CSR segmented reductions ------------------------------
// one wave per cell; lane owns 2 channels; skip empty cells entirely
__global__ __launch_bounds__(256) void pool_csr(const float* __restrict__ net,
                                                const int* __restrict__ perm,
                                                const int* __restrict__ offsets,
                                                float* __restrict__ cellf) {
  const int cellk = blockIdx.x * 4 + (threadIdx.x >> 6);
  const int lane = threadIdx.x & 63;
  const int s0 = offsets[cellk], s1 = offsets[cellk + 1];
  if (s0 >= s1) return;
  float2 m = {-3.402823466e38f, -3.402823466e38f};
  for (int j = s0; j < s1; ++j) {
    const long row = perm[j];
    float2 v = *(const float2*)(net + row * HID + lane * 2);
    m.x = fmaxf(m.x, v.x);
    m.y = fmaxf(m.y, v.y);
  }
  *(float2*)(cellf + (long)cellk * HID + lane * 2) = m;
}

__global__ __launch_bounds__(256) void cellsum_csr(
    const float* __restrict__ c, const int* __restrict__ perm,
    const int* __restrict__ offsets, float* __restrict__ sums) {
  const int cellk = blockIdx.x * 4 + (threadIdx.x >> 6);
  const int lane = threadIdx.x & 63;
  const int s0 = offsets[cellk], s1 = offsets[cellk + 1];
  if (s0 >= s1) return;
  float2 m = {0.f, 0.f};
  for (int j = s0; j < s1; ++j) {
    const long row = perm[j];
    float2 v = *(const float2*)(c + row * HID + lane * 2);
    m.x += v.x;
    m.y += v.y;
  }
  *(float2*)(sums + (long)cellk * HID + lane * 2) = m;
}

__global__ void mean_kernel(const float* __restrict__ sums,
                            const int* __restrict__ offsets,
                            float* __restrict__ out) {
  const long gid = (long)blockIdx.x * 256 + threadIdx.x;
  if (gid >= (long)NB * HID * GCELLS) return;
  const int g = (int)(gid % GCELLS);
  const int c = (int)((gid / GCELLS) % HID);
  const int b = (int)(gid / ((long)HID * GCELLS));
  const int cellk = b * GCELLS + g;
  const int cnt = offsets[cellk + 1] - offsets[cellk];
  out[gid] = cnt > 0 ? sums[(long)cellk * HID + c] / (float)cnt : 0.f;
}

extern "C" void kernel_launch(void* const* d_in, const int* in_sizes, int n_in,
                              void* d_out, int out_size, void* d_ws,
                              size_t ws_size, hipStream_t stream) {
  const float* points = (const float*)d_in[0];
  const int* idx = (const int*)d_in[1];
  const float* fc_pos_w = (const float*)d_in[2];
  const float* fc_pos_b = (const float*)d_in[3];
  const float* fc0_w = (const float*)d_in[4];
  const float* fc0_b = (const float*)d_in[5];
  const float* fc1_w = (const float*)d_in[6];
  const float* fc1_b = (const float*)d_in[7];
  const float* sc_w = (const float*)d_in[8];
  const float* fc_c_w = (const float*)d_in[9];
  const float* fc_c_b = (const float*)d_in[10];
  float* out = (float*)d_out;

  const long NET_BYTES = (long)NB * T_PTS * HID * 4;    // 102,400,000
  const long CELL_BYTES = (long)NB * GCELLS * HID * 4;  // 33,554,432
  float* net = (float*)d_ws;
  float* cellf = (float*)((char*)d_ws + NET_BYTES);
  float* sums = cellf;  // reused after last pooling
  int* offsets = (int*)((char*)d_ws + NET_BYTES + CELL_BYTES);  // 65537 ints

  // scratch in d_out's dead region (overwritten by mean_kernel at the end):
  // packs: 851,968 u16 = 1.7 MB; curs @2 MB (256 KB); perm @3 MB (800 KB)
  unsigned short* packs = (unsigned short*)d_out;
  unsigned short* w0p = packs;            // 5 * 65536
  unsigned short* swp = packs + 327680;   // 5 * 65536
  unsigned short* w1p = packs + 655360;   // 5 * 32768
  unsigned short* wcp = packs + 819200;   // 32768
  int* curs = (int*)((char*)d_out + (2l << 20));
  int* perm = (int*)((char*)d_out + (3l << 20));

  const int GRID_PTS = (NB * T_PTS + 255) / 256;  // 782
  const int GRID_ZERO = (NCELL + 255) / 256;      // 256
  const int GRID_CELL = NCELL / 4;                // 16384
  const int GRID_MEAN = NB * HID * GCELLS / 256;  // 32768

  pack_weights<<<1664, 256, 0, stream>>>(fc0_w, fc1_w, sc_w, fc_c_w, w0p, w1p,
                                         swp, wcp);

  // CSR build (idx is constant across all poolings)
  zero_i32<<<GRID_ZERO, 256, 0, stream>>>(curs, NCELL);
  count_csr<<<GRID_PTS, 256, 0, stream>>>(idx, curs);
  scan_csr<<<1, 1024, 0, stream>>>(curs, offsets);
  zero_i32<<<GRID_ZERO, 256, 0, stream>>>(curs, NCELL);
  scatter_csr<<<GRID_PTS, 256, 0, stream>>>(idx, offsets, curs, perm);

  resblock_mfma<0><<<GRID_RB, 256, 65536, stream>>>(
      points, fc_pos_w, fc_pos_b, nullptr, nullptr, w0p, fc0_b, w1p, fc1_b,
      swp, net);

  for (int i = 1; i < 5; ++i) {
    pool_csr<<<GRID_CELL, 256, 0, stream>>>(net, perm, offsets, cellf);
    resblock_mfma<1><<<GRID_RB, 256, 65536, stream>>>(
        net, nullptr, nullptr, cellf, idx, w0p + (long)i * 65536,
        fc0_b + i * HID, w1p + (long)i * 32768, fc1_b + i * HID,
        swp + (long)i * 65536, net);
  }

  final_mfma<<<GRID_RB, 256, 32768, stream>>>(net, wcp, fc_c_b);
  cellsum_csr<<<GRID_CELL, 256, 0, stream>>>(net, perm, offsets, sums);
  mean_kernel<<<GRID_MEAN, 256, 0, stream>>>(sums, offsets, out);
}

// Round 4
// 784.088 us; speedup vs baseline: 7.8465x; 1.1035x over previous
//
#include <hip/hip_runtime.h>

#define T_PTS 100000
#define NB 2
#define GCELLS 32768
#define NCELL (NB * GCELLS)
#define HID 128
#define MBLK 64
#define RBPB 1563                /* ceil(100000/64) */
#define GRID_RB (NB * RBPB)

typedef __attribute__((ext_vector_type(8))) short bf16x8;
typedef __attribute__((ext_vector_type(4))) float f32x4;

#define MFMA16 __builtin_amdgcn_mfma_f32_16x16x32_bf16

__device__ __forceinline__ unsigned short bf16rne(float f) {
  unsigned u = __float_as_uint(f);
  return (unsigned short)((u + 0x7FFFu + ((u >> 16) & 1u)) >> 16);
}

// ---------------------------------------------------------------------------
// Fused resnet block. 64 points/block, 4 waves, each wave 64 rows x 32 cols
// (wc in 0..3, nt in 0..1, mt in 0..3) of 16x16x32 bf16 MFMA, split-bf16
// 3-pass. LDS 32 KB: x planes [slot2][plane4: xh,xl,rh,rl][mt4][l64][8].
// After GEMM1+3 the same LDS holds h planes [hi/lo][k2 4][mt4][l64][8]
// with la ^= (la>>3)&7 swizzle.
// ---------------------------------------------------------------------------
template <int MODE>
__global__ __launch_bounds__(256, 4) void resblock_mfma(
    const float* __restrict__ src, const float* __restrict__ posw,
    const float* __restrict__ posb, const float* __restrict__ cell,
    const int* __restrict__ idx, const unsigned short* __restrict__ w0p,
    const float* __restrict__ b0, const unsigned short* __restrict__ w1p,
    const float* __restrict__ b1, const unsigned short* __restrict__ swp,
    float* __restrict__ net_out) {
  __shared__ unsigned short lds[16384];
  const int tid = threadIdx.x;
  const int lane = tid & 63;
  const int wc = tid >> 6;
  const int b = blockIdx.x / RBPB;
  const int t0 = (blockIdx.x % RBPB) * MBLK;
  const int valid = (T_PTS - t0 < MBLK) ? (T_PTS - t0) : MBLK;

  f32x4 accy[4][2], acco[4][2];
#pragma unroll
  for (int i = 0; i < 4; ++i)
#pragma unroll
    for (int j = 0; j < 2; ++j) {
      f32x4 z = {0.f, 0.f, 0.f, 0.f};
      accy[i][j] = z;
      acco[i][j] = z;
    }

  auto stage = [&](int ks) {
    const int slot = ks & 1;
    const int pt = tid >> 2;        // 0..63
    const int kc = (tid & 3) << 3;  // 0,8,16,24
    float xv[8];
    if (MODE == 0) {
      float p0 = 0.f, p1 = 0.f, p2 = 0.f;
      if (pt < valid) {
        const float* pp = src + ((long)b * T_PTS + t0 + pt) * 3;
        p0 = pp[0]; p1 = pp[1]; p2 = pp[2];
      }
      const int kb = ks * 32 + kc;
#pragma unroll
      for (int i = 0; i < 8; i += 4) {
        float4 wa = *(const float4*)(posw + kb + i);
        float4 wb = *(const float4*)(posw + 256 + kb + i);
        float4 wcc = *(const float4*)(posw + 512 + kb + i);
        float4 bb = *(const float4*)(posb + kb + i);
        xv[i + 0] = fmaf(p0, wa.x, fmaf(p1, wb.x, fmaf(p2, wcc.x, bb.x)));
        xv[i + 1] = fmaf(p0, wa.y, fmaf(p1, wb.y, fmaf(p2, wcc.y, bb.y)));
        xv[i + 2] = fmaf(p0, wa.z, fmaf(p1, wb.z, fmaf(p2, wcc.z, bb.z)));
        xv[i + 3] = fmaf(p0, wa.w, fmaf(p1, wb.w, fmaf(p2, wcc.w, bb.w)));
      }
    } else {
      if (pt < valid) {
        const float* rp;
        if (ks < 4) {
          rp = src + ((long)b * T_PTS + t0 + pt) * HID + ks * 32 + kc;
        } else {
          const int g = idx[(long)b * T_PTS + t0 + pt];
          rp = cell + ((long)b * GCELLS + g) * HID + (ks - 4) * 32 + kc;
        }
        float4 v0 = *(const float4*)(rp);
        float4 v1 = *(const float4*)(rp + 4);
        xv[0] = v0.x; xv[1] = v0.y; xv[2] = v0.z; xv[3] = v0.w;
        xv[4] = v1.x; xv[5] = v1.y; xv[6] = v1.z; xv[7] = v1.w;
      } else {
#pragma unroll
        for (int i = 0; i < 8; ++i) xv[i] = 0.f;
      }
    }
    bf16x8 vh, vl, vrh, vrl;
#pragma unroll
    for (int i = 0; i < 8; ++i) {
      float x = xv[i];
      unsigned short h = bf16rne(x);
      float hf = __uint_as_float(((unsigned)h) << 16);
      unsigned short lo = bf16rne(x - hf);
      bool pos = x > 0.f;
      vh[i] = (short)h;
      vl[i] = (short)lo;
      vrh[i] = pos ? (short)h : (short)0;
      vrl[i] = pos ? (short)lo : (short)0;
    }
    const int l = (kc >> 3) * 16 + (pt & 15);
    const int base = slot * 8192 + (pt >> 4) * 512 + l * 8;
    *(bf16x8*)(lds + base) = vh;
    *(bf16x8*)(lds + base + 2048) = vl;
    *(bf16x8*)(lds + base + 4096) = vrh;
    *(bf16x8*)(lds + base + 6144) = vrl;
  };

  stage(0);
  __syncthreads();

#pragma unroll 1
  for (int ks = 0; ks < 8; ++ks) {
    if (ks < 7) stage(ks + 1);
    const int slot = ks & 1;
    // pass 1: accy += relu(x) @ w0   (relu planes)
    {
      bf16x8 bh[2], bl[2];
#pragma unroll
      for (int nt = 0; nt < 2; ++nt) {
        const int fi = (ks * 8 + wc * 2 + nt) * 512 + lane * 8;
        bh[nt] = *(const bf16x8*)(w0p + fi);
        bl[nt] = *(const bf16x8*)(w0p + 32768 + fi);
      }
#pragma unroll
      for (int mt = 0; mt < 4; ++mt) {
        const int ab = slot * 8192 + mt * 512 + lane * 8;
        bf16x8 arh = *(const bf16x8*)(lds + ab + 4096);
        bf16x8 arl = *(const bf16x8*)(lds + ab + 6144);
#pragma unroll
        for (int nt = 0; nt < 2; ++nt) {
          accy[mt][nt] = MFMA16(arh, bh[nt], accy[mt][nt], 0, 0, 0);
          accy[mt][nt] = MFMA16(arh, bl[nt], accy[mt][nt], 0, 0, 0);
          accy[mt][nt] = MFMA16(arl, bh[nt], accy[mt][nt], 0, 0, 0);
        }
      }
    }
    // pass 2: acco += x @ sw   (x planes)
    {
      bf16x8 bh[2], bl[2];
#pragma unroll
      for (int nt = 0; nt < 2; ++nt) {
        const int fi = (ks * 8 + wc * 2 + nt) * 512 + lane * 8;
        bh[nt] = *(const bf16x8*)(swp + fi);
        bl[nt] = *(const bf16x8*)(swp + 32768 + fi);
      }
#pragma unroll
      for (int mt = 0; mt < 4; ++mt) {
        const int ab = slot * 8192 + mt * 512 + lane * 8;
        bf16x8 axh = *(const bf16x8*)(lds + ab);
        bf16x8 axl = *(const bf16x8*)(lds + ab + 2048);
#pragma unroll
        for (int nt = 0; nt < 2; ++nt) {
          acco[mt][nt] = MFMA16(axh, bh[nt], acco[mt][nt], 0, 0, 0);
          acco[mt][nt] = MFMA16(axh, bl[nt], acco[mt][nt], 0, 0, 0);
          acco[mt][nt] = MFMA16(axl, bh[nt], acco[mt][nt], 0, 0, 0);
        }
      }
    }
    __syncthreads();
  }

  // h = relu(y + b0) -> h planes in LDS (aliases x buffers), swizzled
  {
    float b0v[2];
#pragma unroll
    for (int nt = 0; nt < 2; ++nt)
      b0v[nt] = b0[wc * 32 + nt * 16 + (lane & 15)];
#pragma unroll
    for (int mt = 0; mt < 4; ++mt) {
#pragma unroll
      for (int nt = 0; nt < 2; ++nt) {
        const int c = wc * 32 + nt * 16 + (lane & 15);
        const int k2 = c >> 5;
        const int j = c & 7;
        const int lahi = ((c & 31) >> 3) * 16;
#pragma unroll
        for (int r = 0; r < 4; ++r) {
          float h = fmaxf(accy[mt][nt][r] + b0v[nt], 0.f);
          unsigned short hh = bf16rne(h);
          float hf = __uint_as_float(((unsigned)hh) << 16);
          unsigned short hl = bf16rne(h - hf);
          int la = lahi + (lane >> 4) * 4 + r;
          la ^= (la >> 3) & 7;
          const int off = ((k2 * 4 + mt) * 64 + la) * 8 + j;
          lds[off] = hh;
          lds[off + 8192] = hl;
        }
      }
    }
  }
  __syncthreads();

  // GEMM2: acco += h @ w1
  {
    const int lar = lane ^ ((lane >> 3) & 7);
#pragma unroll
    for (int k2 = 0; k2 < 4; ++k2) {
      bf16x8 bh[2], bl[2];
#pragma unroll
      for (int nt = 0; nt < 2; ++nt) {
        const int fi = (k2 * 8 + wc * 2 + nt) * 512 + lane * 8;
        bh[nt] = *(const bf16x8*)(w1p + fi);
        bl[nt] = *(const bf16x8*)(w1p + 16384 + fi);
      }
#pragma unroll
      for (int mt = 0; mt < 4; ++mt) {
        const int ab = ((k2 * 4 + mt) * 64 + lar) * 8;
        bf16x8 ah = *(const bf16x8*)(lds + ab);
        bf16x8 al = *(const bf16x8*)(lds + ab + 8192);
#pragma unroll
        for (int nt = 0; nt < 2; ++nt) {
          acco[mt][nt] = MFMA16(ah, bh[nt], acco[mt][nt], 0, 0, 0);
          acco[mt][nt] = MFMA16(ah, bl[nt], acco[mt][nt], 0, 0, 0);
          acco[mt][nt] = MFMA16(al, bh[nt], acco[mt][nt], 0, 0, 0);
        }
      }
    }
  }

  // epilogue: out = acco + b1
  {
    float b1v[2];
#pragma unroll
    for (int nt = 0; nt < 2; ++nt)
      b1v[nt] = b1[wc * 32 + nt * 16 + (lane & 15)];
#pragma unroll
    for (int mt = 0; mt < 4; ++mt) {
#pragma unroll
      for (int r = 0; r < 4; ++r) {
        const int row = mt * 16 + (lane >> 4) * 4 + r;
        if (row < valid) {
          float* op = net_out + ((long)b * T_PTS + t0 + row) * HID;
          op[wc * 32 + (lane & 15)] = acco[mt][0][r] + b1v[0];
          op[wc * 32 + 16 + (lane & 15)] = acco[mt][1][r] + b1v[1];
        }
      }
    }
  }
}

// ---------------------------------------------------------------------------
// final: c = net @ fc_c_w + fc_c_b, written IN-PLACE back into net rows.
// Same 64x(4x32) structure, K=128, hi/lo planes only (16 KB LDS).
// ---------------------------------------------------------------------------
__global__ __launch_bounds__(256, 4) void final_mfma(
    float* __restrict__ net, const unsigned short* __restrict__ wcp,
    const float* __restrict__ bc) {
  __shared__ unsigned short lds[8192];
  const int tid = threadIdx.x;
  const int lane = tid & 63;
  const int wc = tid >> 6;
  const int b = blockIdx.x / RBPB;
  const int t0 = (blockIdx.x % RBPB) * MBLK;
  const int valid = (T_PTS - t0 < MBLK) ? (T_PTS - t0) : MBLK;

  f32x4 acc[4][2];
#pragma unroll
  for (int i = 0; i < 4; ++i)
#pragma unroll
    for (int j = 0; j < 2; ++j) {
      f32x4 z = {0.f, 0.f, 0.f, 0.f};
      acc[i][j] = z;
    }

  auto stage = [&](int ks) {
    const int slot = ks & 1;
    const int pt = tid >> 2;
    const int kc = (tid & 3) << 3;
    float xv[8];
    if (pt < valid) {
      const float* rp = net + ((long)b * T_PTS + t0 + pt) * HID + ks * 32 + kc;
      float4 v0 = *(const float4*)(rp);
      float4 v1 = *(const float4*)(rp + 4);
      xv[0] = v0.x; xv[1] = v0.y; xv[2] = v0.z; xv[3] = v0.w;
      xv[4] = v1.x; xv[5] = v1.y; xv[6] = v1.z; xv[7] = v1.w;
    } else {
#pragma unroll
      for (int i = 0; i < 8; ++i) xv[i] = 0.f;
    }
    bf16x8 vh, vl;
#pragma unroll
    for (int i = 0; i < 8; ++i) {
      float x = xv[i];
      unsigned short h = bf16rne(x);
      float hf = __uint_as_float(((unsigned)h) << 16);
      unsigned short lo = bf16rne(x - hf);
      vh[i] = (short)h;
      vl[i] = (short)lo;
    }
    const int l = (kc >> 3) * 16 + (pt & 15);
    const int base = slot * 4096 + (pt >> 4) * 512 + l * 8;
    *(bf16x8*)(lds + base) = vh;
    *(bf16x8*)(lds + base + 2048) = vl;
  };

  stage(0);
  __syncthreads();
#pragma unroll 1
  for (int ks = 0; ks < 4; ++ks) {
    if (ks < 3) stage(ks + 1);
    const int slot = ks & 1;
    bf16x8 bh[2], bl[2];
#pragma unroll
    for (int nt = 0; nt < 2; ++nt) {
      const int fi = (ks * 8 + wc * 2 + nt) * 512 + lane * 8;
      bh[nt] = *(const bf16x8*)(wcp + fi);
      bl[nt] = *(const bf16x8*)(wcp + 16384 + fi);
    }
#pragma unroll
    for (int mt = 0; mt < 4; ++mt) {
      const int ab = slot * 4096 + mt * 512 + lane * 8;
      bf16x8 ah = *(const bf16x8*)(lds + ab);
      bf16x8 al = *(const bf16x8*)(lds + ab + 2048);
#pragma unroll
      for (int nt = 0; nt < 2; ++nt) {
        acc[mt][nt] = MFMA16(ah, bh[nt], acc[mt][nt], 0, 0, 0);
        acc[mt][nt] = MFMA16(ah, bl[nt], acc[mt][nt], 0, 0, 0);
        acc[mt][nt] = MFMA16(al, bh[nt], acc[mt][nt], 0, 0, 0);
      }
    }
    __syncthreads();
  }

  float bcv[2];
#pragma unroll
  for (int nt = 0; nt < 2; ++nt)
    bcv[nt] = bc[wc * 32 + nt * 16 + (lane & 15)];
#pragma unroll
  for (int mt = 0; mt < 4; ++mt) {
#pragma unroll
    for (int r = 0; r < 4; ++r) {
      const int row = mt * 16 + (lane >> 4) * 4 + r;
      if (row < valid) {
        float* op = net + ((long)b * T_PTS + t0 + row) * HID;
        op[wc * 32 + (lane & 15)] = acc[mt][0][r] + bcv[0];
        op[wc * 32 + 16 + (lane & 15)] = acc[mt][1][r] + bcv[1];
      }
    }
  }
}

// ---------------------------------------------------------------------------
// one-time weight pack: fp32 (K,128) -> bf16 hi/lo planes in MFMA-B-frag order
// ---------------------------------------------------------------------------
__global__ void pack_weights(const float* __restrict__ fc0,
                             const float* __restrict__ fc1,
                             const float* __restrict__ sc,
                             const float* __restrict__ fcc,
                             unsigned short* __restrict__ w0p,
                             unsigned short* __restrict__ w1p,
                             unsigned short* __restrict__ swp,
                             unsigned short* __restrict__ wcp) {
  int gid = blockIdx.x * 256 + threadIdx.x;
  const float* src;
  unsigned short* dst;
  int K, e;
  if (gid < 163840) { src = fc0; dst = w0p; K = 256; e = gid; }
  else if (gid < 327680) { src = sc; dst = swp; K = 256; e = gid - 163840; }
  else if (gid < 409600) { src = fc1; dst = w1p; K = 128; e = gid - 327680; }
  else if (gid < 425984) { src = fcc; dst = wcp; K = 128; e = gid - 409600; }
  else return;
  const int mat = e / (K * 128);
  const int r = e - mat * K * 128;
  const int k = r >> 7, n = r & 127;
  const float x = src[e];
  const unsigned short hi = bf16rne(x);
  const float hf = __uint_as_float(((unsigned)hi) << 16);
  const unsigned short lo = bf16rne(x - hf);
  const int ks = k >> 5, lg = (k >> 3) & 3, j = k & 7;
  const int l = lg * 16 + (n & 15), nt = n >> 4;
  unsigned short* mb = dst + (long)mat * K * 256;
  const int off = ((ks * 8 + nt) * 64 + l) * 8 + j;
  mb[off] = hi;
  mb[off + K * 128] = lo;
}

// --------------------------- CSR build -------------------------------------
__global__ void zero_i32(int* __restrict__ p, int n) {
  const int i = blockIdx.x * 256 + threadIdx.x;
  if (i < n) p[i] = 0;
}

__global__ void count_csr(const int* __restrict__ idx, int* __restrict__ curs) {
  const int gid = blockIdx.x * 256 + threadIdx.x;
  if (gid >= NB * T_PTS) return;
  const int b = gid / T_PTS;
  atomicAdd(&curs[b * GCELLS + idx[gid]], 1);
}

__global__ __launch_bounds__(1024) void scan_csr(const int* __restrict__ cnt,
                                                 int* __restrict__ offsets) {
  __shared__ int part[1024];
  const int t = threadIdx.x;
  const int base = t * (NCELL / 1024);
  int s = 0;
  for (int i = 0; i < NCELL / 1024; ++i) s += cnt[base + i];
  part[t] = s;
  __syncthreads();
  for (int d = 1; d < 1024; d <<= 1) {
    int v = (t >= d) ? part[t - d] : 0;
    __syncthreads();
    part[t] += v;
    __syncthreads();
  }
  int run = (t == 0) ? 0 : part[t - 1];
  for (int i = 0; i < NCELL / 1024; ++i) {
    offsets[base + i] = run;
    run += cnt[base + i];
  }
  if (t == 1023) offsets[NCELL] = run;
}

__global__ void scatter_csr(const int* __restrict__ idx,
                            const int* __restrict__ offsets,
                            int* __restrict__ curs, int* __restrict__ perm) {
  const int gid = blockIdx.x * 256 + threadIdx.x;
  if (gid >= NB * T_PTS) return;
  const int b = gid / T_PTS;
  const int cellk = b * GCELLS + idx[gid];
  const int slot = offsets[cellk] + atomicAdd(&curs[cellk], 1);
  perm[slot] = gid;
}

// ------------------- CSR segmented reductions ------------------------------
__global__ __launch_bounds__(256) void pool_csr(const float* __restrict__ net,
                                                const int* __restrict__ perm,
                                                const int* __restrict__ offsets,
                                                float* __restrict__ cellf) {
  const int cellk = blockIdx.x * 4 + (threadIdx.x >> 6);
  const int lane = threadIdx.x & 63;
  const int s0 = offsets[cellk], s1 = offsets[cellk + 1];
  if (s0 >= s1) return;
  float2 m = {-3.402823466e38f, -3.402823466e38f};
  for (int j = s0; j < s1; ++j) {
    const long row = perm[j];
    float2 v = *(const float2*)(net + row * HID + lane * 2);
    m.x = fmaxf(m.x, v.x);
    m.y = fmaxf(m.y, v.y);
  }
  *(float2*)(cellf + (long)cellk * HID + lane * 2) = m;
}

__global__ __launch_bounds__(256) void cellsum_csr(
    const float* __restrict__ c, const int* __restrict__ perm,
    const int* __restrict__ offsets, float* __restrict__ sums) {
  const int cellk = blockIdx.x * 4 + (threadIdx.x >> 6);
  const int lane = threadIdx.x & 63;
  const int s0 = offsets[cellk], s1 = offsets[cellk + 1];
  if (s0 >= s1) return;
  float2 m = {0.f, 0.f};
  for (int j = s0; j < s1; ++j) {
    const long row = perm[j];
    float2 v = *(const float2*)(c + row * HID + lane * 2);
    m.x += v.x;
    m.y += v.y;
  }
  *(float2*)(sums + (long)cellk * HID + lane * 2) = m;
}

__global__ void mean_kernel(const float* __restrict__ sums,
                            const int* __restrict__ offsets,
                            float* __restrict__ out) {
  const long gid = (long)blockIdx.x * 256 + threadIdx.x;
  if (gid >= (long)NB * HID * GCELLS) return;
  const int g = (int)(gid % GCELLS);
  const int c = (int)((gid / GCELLS) % HID);
  const int b = (int)(gid / ((long)HID * GCELLS));
  const int cellk = b * GCELLS + g;
  const int cnt = offsets[cellk + 1] - offsets[cellk];
  out[gid] = cnt > 0 ? sums[(long)cellk * HID + c] / (float)cnt : 0.f;
}

extern "C" void kernel_launch(void* const* d_in, const int* in_sizes, int n_in,
                              void* d_out, int out_size, void* d_ws,
                              size_t ws_size, hipStream_t stream) {
  const float* points = (const float*)d_in[0];
  const int* idx = (const int*)d_in[1];
  const float* fc_pos_w = (const float*)d_in[2];
  const float* fc_pos_b = (const float*)d_in[3];
  const float* fc0_w = (const float*)d_in[4];
  const float* fc0_b = (const float*)d_in[5];
  const float* fc1_w = (const float*)d_in[6];
  const float* fc1_b = (const float*)d_in[7];
  const float* sc_w = (const float*)d_in[8];
  const float* fc_c_w = (const float*)d_in[9];
  const float* fc_c_b = (const float*)d_in[10];
  float* out = (float*)d_out;

  const long NET_BYTES = (long)NB * T_PTS * HID * 4;    // 102,400,000
  const long CELL_BYTES = (long)NB * GCELLS * HID * 4;  // 33,554,432
  float* net = (float*)d_ws;
  float* cellf = (float*)((char*)d_ws + NET_BYTES);
  float* sums = cellf;  // reused after last pooling
  int* offsets = (int*)((char*)d_ws + NET_BYTES + CELL_BYTES);  // 65537 ints

  // scratch in d_out's dead region (overwritten by mean_kernel at the end)
  unsigned short* packs = (unsigned short*)d_out;
  unsigned short* w0p = packs;            // 5 * 65536
  unsigned short* swp = packs + 327680;   // 5 * 65536
  unsigned short* w1p = packs + 655360;   // 5 * 32768
  unsigned short* wcp = packs + 819200;   // 32768
  int* curs = (int*)((char*)d_out + (2l << 20));
  int* perm = (int*)((char*)d_out + (3l << 20));

  const int GRID_PTS = (NB * T_PTS + 255) / 256;  // 782
  const int GRID_ZERO = (NCELL + 255) / 256;      // 256
  const int GRID_CELL = NCELL / 4;                // 16384
  const int GRID_MEAN = NB * HID * GCELLS / 256;  // 32768

  pack_weights<<<1664, 256, 0, stream>>>(fc0_w, fc1_w, sc_w, fc_c_w, w0p, w1p,
                                         swp, wcp);

  zero_i32<<<GRID_ZERO, 256, 0, stream>>>(curs, NCELL);
  count_csr<<<GRID_PTS, 256, 0, stream>>>(idx, curs);
  scan_csr<<<1, 1024, 0, stream>>>(curs, offsets);
  zero_i32<<<GRID_ZERO, 256, 0, stream>>>(curs, NCELL);
  scatter_csr<<<GRID_PTS, 256, 0, stream>>>(idx, offsets, curs, perm);

  resblock_mfma<0><<<GRID_RB, 256, 0, stream>>>(
      points, fc_pos_w, fc_pos_b, nullptr, nullptr, w0p, fc0_b, w1p, fc1_b,
      swp, net);

  for (int i = 1; i < 5; ++i) {
    pool_csr<<<GRID_CELL, 256, 0, stream>>>(net, perm, offsets, cellf);
    resblock_mfma<1><<<GRID_RB, 256, 0, stream>>>(
        net, nullptr, nullptr, cellf, idx, w0p + (long)i * 65536,
        fc0_b + i * HID, w1p + (long)i * 32768, fc1_b + i * HID,
        swp + (long)i * 65536, net);
  }

  final_mfma<<<GRID_RB, 256, 0, stream>>>(net, wcp, fc_c_b);
  cellsum_csr<<<GRID_CELL, 256, 0, stream>>>(net, perm, offsets, sums);
  mean_kernel<<<GRID_MEAN, 256, 0, stream>>>(sums, offsets, out);
}